// Round 3
// baseline (1278.006 us; speedup 1.0000x reference)
//
#include <hip/hip_runtime.h>

#define NN 50000
#define D 128
#define EE 600000
#define R 8
#define NR (NN * R)            /* 400000 segments */
#define NCHUNK 36              /* 1152 / 32 k-chunks */
#define SCAN_CHUNK 1024
#define NSB ((NR + SCAN_CHUNK - 1) / SCAN_CHUNK) /* 391 */
#define APAD 132               /* 128 + 4 pad: 2-way (free) LDS bank alias */

typedef unsigned short u16;
typedef __attribute__((ext_vector_type(8))) short bf16x8;
typedef __attribute__((ext_vector_type(4))) float f32x4;

__device__ inline u16 f2bf(float f) {
    union { float f; unsigned u; } v; v.f = f;
    unsigned r = (v.u + 0x7FFFu + ((v.u >> 16) & 1u)) >> 16;
    return (u16)r;
}

// ---- histogram per segment key = rel*N + dst ----
__global__ __launch_bounds__(256) void hist_kernel(const int* __restrict__ dst,
                                                   const int* __restrict__ et,
                                                   int* __restrict__ cnt, int E) {
    int e = blockIdx.x * 256 + threadIdx.x;
    if (e < E) atomicAdd(&cnt[et[e] * NN + dst[e]], 1);
}

// ---- exclusive scan, 3-pass (chunk=1024, 4 elems/thread) ----
__global__ __launch_bounds__(256) void scanA(const int* __restrict__ cnt,
                                             int* __restrict__ off,
                                             int* __restrict__ bsum) {
    __shared__ int ts[256];
    const int b = blockIdx.x, t = threadIdx.x;
    const int base = b * SCAN_CHUNK + t * 4;
    int v0 = 0, v1 = 0, v2 = 0, v3 = 0;
    if (base + 3 < NR) {
        int4 q = *(const int4*)(cnt + base);
        v0 = q.x; v1 = q.y; v2 = q.z; v3 = q.w;
    } else {
        if (base < NR) v0 = cnt[base];
        if (base + 1 < NR) v1 = cnt[base + 1];
        if (base + 2 < NR) v2 = cnt[base + 2];
    }
    const int s = v0 + v1 + v2 + v3;
    ts[t] = s;
    __syncthreads();
    for (int d = 1; d < 256; d <<= 1) {
        int x = (t >= d) ? ts[t - d] : 0;
        __syncthreads();
        ts[t] += x;
        __syncthreads();
    }
    const int excl = ts[t] - s;
    if (base < NR) off[base] = excl;
    if (base + 1 < NR) off[base + 1] = excl + v0;
    if (base + 2 < NR) off[base + 2] = excl + v0 + v1;
    if (base + 3 < NR) off[base + 3] = excl + v0 + v1 + v2;
    if (t == 255) bsum[b] = ts[255];
}

__global__ __launch_bounds__(512) void scanB(const int* __restrict__ bsum,
                                             int* __restrict__ boff) {
    __shared__ int ts[512];
    const int t = threadIdx.x;
    const int v = (t < NSB) ? bsum[t] : 0;
    ts[t] = v;
    __syncthreads();
    for (int d = 1; d < 512; d <<= 1) {
        int x = (t >= d) ? ts[t - d] : 0;
        __syncthreads();
        ts[t] += x;
        __syncthreads();
    }
    if (t < NSB) boff[t] = ts[t] - v;
}

__global__ __launch_bounds__(256) void scanC(int* __restrict__ off,
                                             const int* __restrict__ boff) {
    const int b = blockIdx.x, t = threadIdx.x;
    const int add = boff[b];
    const int base = b * SCAN_CHUNK + t * 4;
#pragma unroll
    for (int j = 0; j < 4; ++j)
        if (base + j < NR) off[base + j] += add;
    if (b == 0 && t == 0) off[NR] = EE;
}

// ---- place edges into sorted order ----
__global__ __launch_bounds__(256) void place_kernel(const int* __restrict__ src,
                                                    const int* __restrict__ dst,
                                                    const int* __restrict__ et,
                                                    int* __restrict__ cursor,
                                                    int* __restrict__ ss,
                                                    int* __restrict__ dd, int E) {
    int e = blockIdx.x * 256 + threadIdx.x;
    if (e < E) {
        int key = et[e] * NN + dst[e];
        int p = atomicAdd(&cursor[key], 1);
        ss[p] = src[e];
        dd[p] = dst[e];
    }
}

// ---- pack B = [w (1024x128); root (128x128)] into bf16 MFMA B-fragment order ----
__global__ __launch_bounds__(256) void bprep_kernel(const float* __restrict__ w,
                                                    const float* __restrict__ root,
                                                    u16* __restrict__ Bfrag) {
    int idx = blockIdx.x * 256 + threadIdx.x;  // over 36*8*64 = 18432
    if (idx >= NCHUNK * 8 * 64) return;
    int lane = idx & 63;
    int g = (idx >> 6) & 7;
    int kc = idx >> 9;
    int col = g * 16 + (lane & 15);
    int kbase = kc * 32 + (lane >> 4) * 8;
    u16* o = Bfrag + (size_t)idx * 8;
#pragma unroll
    for (int j = 0; j < 8; ++j) {
        int k = kbase + j;
        float v = (k < R * D) ? w[(size_t)k * D + col]
                              : root[(size_t)(k - R * D) * D + col];
        o[j] = f2bf(v);
    }
}

// ---- fused: per-relation LDS aggregation + MFMA + root + bias + relu ----
__global__ __launch_bounds__(256) void rgcn_fused(const float* __restrict__ xin,
                                                  const int* __restrict__ off,
                                                  const int* __restrict__ srcs,
                                                  const int* __restrict__ dsts,
                                                  const u16* __restrict__ Bfrag,
                                                  const float* __restrict__ bias,
                                                  float* __restrict__ out) {
    __shared__ float Asub[64][APAD];
    __shared__ int offs_s[65];

    const int t = threadIdx.x;
    const int wave = t >> 6;
    const int lane = t & 63;
    const int quad = lane >> 4;
    const int l15 = lane & 15;
    const int n0 = blockIdx.x * 64;
    const int frow = wave * 16 + l15;  // A-fragment row (m)

    f32x4 acc[8];
#pragma unroll
    for (int g = 0; g < 8; ++g) acc[g] = (f32x4){0.f, 0.f, 0.f, 0.f};

    const u16* bbase = Bfrag + (size_t)lane * 8;

#pragma unroll 1
    for (int r = 0; r < R; ++r) {
        // segment offsets for this relation's 64 nodes (clamped at N)
        if (t <= 64) {
            int nid = n0 + t;
            if (nid > NN) nid = NN;
            offs_s[t] = off[r * NN + nid];
        }
        // zero the tile: thread t zeros 32 floats of row t>>2
        {
            float4* zp = (float4*)&Asub[t >> 2][(t & 3) * 32];
#pragma unroll
            for (int j = 0; j < 8; ++j) zp[j] = make_float4(0.f, 0.f, 0.f, 0.f);
        }
        __syncthreads();

        const int e0 = offs_s[0], e1 = offs_s[64];
        for (int i = e0 + wave; i < e1; i += 4) {
            const int s = srcs[i];
            const int row = dsts[i] - n0;
            const float* xs = xin + (size_t)s * D;
            atomicAdd(&Asub[row][lane], xs[lane]);
            atomicAdd(&Asub[row][lane + 64], xs[lane + 64]);
        }
        __syncthreads();

        const int cnt = offs_s[frow + 1] - offs_s[frow];
        const float invs = 1.0f / fmaxf((float)cnt, 1.0f);
#pragma unroll
        for (int c = 0; c < 4; ++c) {
            const float* ap = &Asub[frow][c * 32 + quad * 8];
            float4 v0 = *(const float4*)ap;
            float4 v1 = *(const float4*)(ap + 4);
            bf16x8 af;
            af[0] = (short)f2bf(v0.x * invs); af[1] = (short)f2bf(v0.y * invs);
            af[2] = (short)f2bf(v0.z * invs); af[3] = (short)f2bf(v0.w * invs);
            af[4] = (short)f2bf(v1.x * invs); af[5] = (short)f2bf(v1.y * invs);
            af[6] = (short)f2bf(v1.z * invs); af[7] = (short)f2bf(v1.w * invs);
            const int kc = r * 4 + c;
#pragma unroll
            for (int g = 0; g < 8; ++g) {
                bf16x8 bf = *(const bf16x8*)(bbase + (size_t)(kc * 8 + g) * 512);
                acc[g] = __builtin_amdgcn_mfma_f32_16x16x32_bf16(af, bf, acc[g], 0, 0, 0);
            }
        }
        __syncthreads();
    }

    // root part: k = 1024..1151 from xin directly (unscaled)
    {
        const int n = n0 + frow;
        const int nc = (n < NN) ? n : (NN - 1);
        const float* xrow = xin + (size_t)nc * D + quad * 8;
#pragma unroll
        for (int c = 0; c < 4; ++c) {
            float4 v0 = *(const float4*)(xrow + c * 32);
            float4 v1 = *(const float4*)(xrow + c * 32 + 4);
            bf16x8 af;
            af[0] = (short)f2bf(v0.x); af[1] = (short)f2bf(v0.y);
            af[2] = (short)f2bf(v0.z); af[3] = (short)f2bf(v0.w);
            af[4] = (short)f2bf(v1.x); af[5] = (short)f2bf(v1.y);
            af[6] = (short)f2bf(v1.z); af[7] = (short)f2bf(v1.w);
            const int kc = 32 + c;
#pragma unroll
            for (int g = 0; g < 8; ++g) {
                bf16x8 bf = *(const bf16x8*)(bbase + (size_t)(kc * 8 + g) * 512);
                acc[g] = __builtin_amdgcn_mfma_f32_16x16x32_bf16(af, bf, acc[g], 0, 0, 0);
            }
        }
    }

    // epilogue: bias + relu; D mapping: row = quad*4 + q, col = g*16 + l15
#pragma unroll
    for (int g = 0; g < 8; ++g) {
        const int col = g * 16 + l15;
        const float bb = bias[col];
#pragma unroll
        for (int q = 0; q < 4; ++q) {
            const int row = n0 + wave * 16 + quad * 4 + q;
            if (row < NN)
                out[(size_t)row * D + col] = fmaxf(acc[g][q] + bb, 0.f);
        }
    }
}

extern "C" void kernel_launch(void* const* d_in, const int* in_sizes, int n_in,
                              void* d_out, int out_size, void* d_ws, size_t ws_size,
                              hipStream_t stream) {
    const float* x = (const float*)d_in[0];
    const int* ei = (const int*)d_in[1];
    const int* et = (const int*)d_in[2];
    const float* w1 = (const float*)d_in[3];
    const float* root1 = (const float*)d_in[4];
    const float* b1 = (const float*)d_in[5];
    const float* w2 = (const float*)d_in[6];
    const float* root2 = (const float*)d_in[7];
    const float* b2 = (const float*)d_in[8];
    float* out = (float*)d_out;

    char* ws = (char*)d_ws;
    int* off    = (int*)(ws + 0);                 // (NR+1) ints
    int* cnt_i  = (int*)(ws + 1600512);           // NR ints
    int* cursor = (int*)(ws + 3200512);           // NR ints
    int* bsum   = (int*)(ws + 4800512);           // NSB ints
    int* boff   = (int*)(ws + 4802304);           // NSB ints
    int* srcs   = (int*)(ws + 4804096);           // EE ints
    int* dsts   = (int*)(ws + 7204096);           // EE ints
    float* h    = (float*)(ws + 9604096);         // N*D fp32
    u16* Bf1    = (u16*)(ws + 35204096);          // 294912 B
    u16* Bf2    = (u16*)(ws + 35499008);          // 294912 B

    const int* srcp = ei;
    const int* dstp = ei + EE;

    // ---- build CSR (shared by both layers) ----
    hipMemsetAsync(cnt_i, 0, (size_t)NR * sizeof(int), stream);
    hist_kernel<<<(EE + 255) / 256, 256, 0, stream>>>(dstp, et, cnt_i, EE);
    scanA<<<NSB, 256, 0, stream>>>(cnt_i, off, bsum);
    scanB<<<1, 512, 0, stream>>>(bsum, boff);
    scanC<<<NSB, 256, 0, stream>>>(off, boff);
    hipMemcpyAsync(cursor, off, (size_t)NR * sizeof(int),
                   hipMemcpyDeviceToDevice, stream);
    place_kernel<<<(EE + 255) / 256, 256, 0, stream>>>(srcp, dstp, et, cursor,
                                                       srcs, dsts, EE);

    // ---- pack weights ----
    bprep_kernel<<<(NCHUNK * 8 * 64 + 255) / 256, 256, 0, stream>>>(w1, root1, Bf1);
    bprep_kernel<<<(NCHUNK * 8 * 64 + 255) / 256, 256, 0, stream>>>(w2, root2, Bf2);

    const int blocks = (NN + 63) / 64;  // 782

    // layer 1: x -> h ; layer 2: h -> out
    rgcn_fused<<<blocks, 256, 0, stream>>>(x, off, srcs, dsts, Bf1, b1, h);
    rgcn_fused<<<blocks, 256, 0, stream>>>(h, off, srcs, dsts, Bf2, b2, out);
}

// Round 4
// 474.310 us; speedup vs baseline: 2.6945x; 2.6945x over previous
//
#include <hip/hip_runtime.h>

#define NN 50000
#define D 128
#define EE 600000
#define R 8
#define NR (NN * R)            /* 400000 segments, key = dst*R + rel (node-major) */
#define NCHUNK 36              /* 1152 / 32 k-chunks */
#define SCAN_CHUNK 1024
#define NSB ((NR + SCAN_CHUNK - 1) / SCAN_CHUNK) /* 391 */

typedef unsigned short u16;
typedef unsigned int u32;
typedef __attribute__((ext_vector_type(8))) short bf16x8;
typedef __attribute__((ext_vector_type(4))) float f32x4;

__device__ inline u16 f2bf(float f) {
    union { float f; u32 u; } v; v.f = f;
    return (u16)((v.u + 0x7FFFu + ((v.u >> 16) & 1u)) >> 16);
}
__device__ inline float bf2f(u16 h) {
    union { u32 u; float f; } v; v.u = ((u32)h) << 16;
    return v.f;
}

// ---- histogram per segment key = dst*R + rel ----
__global__ __launch_bounds__(256) void hist_kernel(const int* __restrict__ dst,
                                                   const int* __restrict__ et,
                                                   int* __restrict__ cnt, int E) {
    int e = blockIdx.x * 256 + threadIdx.x;
    if (e < E) atomicAdd(&cnt[dst[e] * R + et[e]], 1);
}

// ---- exclusive scan, 3-pass ----
__global__ __launch_bounds__(256) void scanA(const int* __restrict__ cnt,
                                             int* __restrict__ off,
                                             int* __restrict__ bsum) {
    __shared__ int ts[256];
    const int b = blockIdx.x, t = threadIdx.x;
    const int base = b * SCAN_CHUNK + t * 4;
    int v0 = 0, v1 = 0, v2 = 0, v3 = 0;
    if (base + 3 < NR) {
        int4 q = *(const int4*)(cnt + base);
        v0 = q.x; v1 = q.y; v2 = q.z; v3 = q.w;
    } else {
        if (base < NR) v0 = cnt[base];
        if (base + 1 < NR) v1 = cnt[base + 1];
        if (base + 2 < NR) v2 = cnt[base + 2];
    }
    const int s = v0 + v1 + v2 + v3;
    ts[t] = s;
    __syncthreads();
    for (int d = 1; d < 256; d <<= 1) {
        int x = (t >= d) ? ts[t - d] : 0;
        __syncthreads();
        ts[t] += x;
        __syncthreads();
    }
    const int excl = ts[t] - s;
    if (base < NR) off[base] = excl;
    if (base + 1 < NR) off[base + 1] = excl + v0;
    if (base + 2 < NR) off[base + 2] = excl + v0 + v1;
    if (base + 3 < NR) off[base + 3] = excl + v0 + v1 + v2;
    if (t == 255) bsum[b] = ts[255];
}

__global__ __launch_bounds__(512) void scanB(const int* __restrict__ bsum,
                                             int* __restrict__ boff) {
    __shared__ int ts[512];
    const int t = threadIdx.x;
    const int v = (t < NSB) ? bsum[t] : 0;
    ts[t] = v;
    __syncthreads();
    for (int d = 1; d < 512; d <<= 1) {
        int x = (t >= d) ? ts[t - d] : 0;
        __syncthreads();
        ts[t] += x;
        __syncthreads();
    }
    if (t < NSB) boff[t] = ts[t] - v;
}

__global__ __launch_bounds__(256) void scanC(int* __restrict__ off,
                                             const int* __restrict__ boff) {
    const int b = blockIdx.x, t = threadIdx.x;
    const int add = boff[b];
    const int base = b * SCAN_CHUNK + t * 4;
#pragma unroll
    for (int j = 0; j < 4; ++j)
        if (base + j < NR) off[base + j] += add;
    if (b == 0 && t == 0) off[NR] = EE;
}

// ---- place edge sources into segment-sorted order ----
__global__ __launch_bounds__(256) void place_kernel(const int* __restrict__ src,
                                                    const int* __restrict__ dst,
                                                    const int* __restrict__ et,
                                                    int* __restrict__ cursor,
                                                    int* __restrict__ ss, int E) {
    int e = blockIdx.x * 256 + threadIdx.x;
    if (e < E) {
        int key = dst[e] * R + et[e];
        int p = atomicAdd(&cursor[key], 1);
        ss[p] = src[e];
    }
}

// ---- pack B = [w (1024x128); root (128x128)] into bf16 MFMA B-fragment order ----
__global__ __launch_bounds__(256) void bprep_kernel(const float* __restrict__ w,
                                                    const float* __restrict__ root,
                                                    u16* __restrict__ Bfrag) {
    int idx = blockIdx.x * 256 + threadIdx.x;  // over 36*8*64 = 18432
    if (idx >= NCHUNK * 8 * 64) return;
    int lane = idx & 63;
    int g = (idx >> 6) & 7;
    int kc = idx >> 9;
    int col = g * 16 + (lane & 15);
    int kbase = kc * 32 + (lane >> 4) * 8;
    u16* o = Bfrag + (size_t)idx * 8;
#pragma unroll
    for (int j = 0; j < 8; ++j) {
        int k = kbase + j;
        float v = (k < R * D) ? w[(size_t)k * D + col]
                              : root[(size_t)(k - R * D) * D + col];
        o[j] = f2bf(v);
    }
}

// ---- segment mean: one wave per (node,rel) segment; pre-scaled bf16 output ----
// mean[(n*R+r)*D + d] so rows are GEMM-ready (k contiguous).
template <bool INBF>
__global__ __launch_bounds__(256) void seg_mean(const void* __restrict__ xin,
                                                const int* __restrict__ off,
                                                const int* __restrict__ srcs,
                                                u32* __restrict__ mean) {
    const int seg = blockIdx.x * 4 + (threadIdx.x >> 6);
    const int lane = threadIdx.x & 63;
    const int e0 = off[seg], e1 = off[seg + 1];
    float ax = 0.f, ay = 0.f;
    for (int i = e0; i < e1; ++i) {
        const int s = srcs[i];
        if (INBF) {
            u32 v = ((const u32*)xin)[(size_t)s * (D / 2) + lane];
            ax += bf2f((u16)(v & 0xFFFFu));
            ay += bf2f((u16)(v >> 16));
        } else {
            float2 v = ((const float2*)xin)[(size_t)s * (D / 2) + lane];
            ax += v.x;
            ay += v.y;
        }
    }
    const float inv = (e1 > e0) ? 1.0f / (float)(e1 - e0) : 0.f;
    mean[(size_t)seg * (D / 2) + lane] =
        (u32)f2bf(ax * inv) | ((u32)f2bf(ay * inv) << 16);
}

// ---- MFMA GEMM: out[n,:] = relu( [mean(n,:,:), xin(n,:)] @ [w;root] + b ) ----
template <bool INBF, bool OUTBF>
__global__ __launch_bounds__(256) void gemm_mfma(const void* __restrict__ xin,
                                                 const u16* __restrict__ mean,
                                                 const u16* __restrict__ Bfrag,
                                                 const float* __restrict__ bias,
                                                 void* __restrict__ outp) {
    const int t = threadIdx.x;
    const int wave = t >> 6;
    const int lane = t & 63;
    const int quad = lane >> 4;
    const int l15 = lane & 15;
    const int n0 = blockIdx.x * 64;
    const int n = n0 + wave * 16 + l15;
    const int nc = (n < NN) ? n : (NN - 1);  // clamp loads; stores guarded

    f32x4 acc[8];
#pragma unroll
    for (int g = 0; g < 8; ++g) acc[g] = (f32x4){0.f, 0.f, 0.f, 0.f};

    const u16* bbase = Bfrag + (size_t)lane * 8;
    const u16* arow = mean + (size_t)nc * (R * D) + quad * 8;

    // relation part: k = 0..1023, bf16 direct from mean (pre-scaled)
#pragma unroll
    for (int kc = 0; kc < 32; ++kc) {
        bf16x8 af = *(const bf16x8*)(arow + kc * 32);
#pragma unroll
        for (int g = 0; g < 8; ++g) {
            bf16x8 bf = *(const bf16x8*)(bbase + (size_t)(kc * 8 + g) * 512);
            acc[g] = __builtin_amdgcn_mfma_f32_16x16x32_bf16(af, bf, acc[g], 0, 0, 0);
        }
    }

    // root part: k = 1024..1151 from xin
#pragma unroll
    for (int c = 0; c < 4; ++c) {
        bf16x8 af;
        if (INBF) {
            const u16* xr = (const u16*)xin + (size_t)nc * D + quad * 8;
            af = *(const bf16x8*)(xr + c * 32);
        } else {
            const float* xr = (const float*)xin + (size_t)nc * D + quad * 8;
            float4 v0 = *(const float4*)(xr + c * 32);
            float4 v1 = *(const float4*)(xr + c * 32 + 4);
            af[0] = (short)f2bf(v0.x); af[1] = (short)f2bf(v0.y);
            af[2] = (short)f2bf(v0.z); af[3] = (short)f2bf(v0.w);
            af[4] = (short)f2bf(v1.x); af[5] = (short)f2bf(v1.y);
            af[6] = (short)f2bf(v1.z); af[7] = (short)f2bf(v1.w);
        }
        const int kc = 32 + c;
#pragma unroll
        for (int g = 0; g < 8; ++g) {
            bf16x8 bf = *(const bf16x8*)(bbase + (size_t)(kc * 8 + g) * 512);
            acc[g] = __builtin_amdgcn_mfma_f32_16x16x32_bf16(af, bf, acc[g], 0, 0, 0);
        }
    }

    // epilogue: bias + relu; D mapping: row = quad*4 + q, col = g*16 + l15
#pragma unroll
    for (int g = 0; g < 8; ++g) {
        const int col = g * 16 + l15;
        const float bb = bias[col];
#pragma unroll
        for (int q = 0; q < 4; ++q) {
            const int row = n0 + wave * 16 + quad * 4 + q;
            if (row < NN) {
                float v = fmaxf(acc[g][q] + bb, 0.f);
                if (OUTBF)
                    ((u16*)outp)[(size_t)row * D + col] = f2bf(v);
                else
                    ((float*)outp)[(size_t)row * D + col] = v;
            }
        }
    }
}

extern "C" void kernel_launch(void* const* d_in, const int* in_sizes, int n_in,
                              void* d_out, int out_size, void* d_ws, size_t ws_size,
                              hipStream_t stream) {
    const float* x = (const float*)d_in[0];
    const int* ei = (const int*)d_in[1];
    const int* et = (const int*)d_in[2];
    const float* w1 = (const float*)d_in[3];
    const float* root1 = (const float*)d_in[4];
    const float* b1 = (const float*)d_in[5];
    const float* w2 = (const float*)d_in[6];
    const float* root2 = (const float*)d_in[7];
    const float* b2 = (const float*)d_in[8];
    float* out = (float*)d_out;

    char* ws = (char*)d_ws;
    int* off    = (int*)(ws + 0);                 // (NR+1) ints
    int* cnt_i  = (int*)(ws + 1600512);           // NR ints
    int* cursor = (int*)(ws + 3200512);           // NR ints
    int* bsum   = (int*)(ws + 4800512);           // NSB ints
    int* boff   = (int*)(ws + 4802304);           // NSB ints
    int* srcs   = (int*)(ws + 4804096);           // EE ints (2.4 MB)
    u32* mean   = (u32*)(ws + 7204096);           // N*R*D bf16 = 102.4 MB
    u16* h      = (u16*)(ws + 7204096 + 102400000);           // N*D bf16 = 12.8 MB
    u16* Bf1    = (u16*)(ws + 7204096 + 102400000 + 12800000);       // 294912 B
    u16* Bf2    = (u16*)(ws + 7204096 + 102400000 + 12800000 + 294912);

    const int* srcp = ei;
    const int* dstp = ei + EE;

    // ---- build CSR (shared by both layers) ----
    hipMemsetAsync(cnt_i, 0, (size_t)NR * sizeof(int), stream);
    hist_kernel<<<(EE + 255) / 256, 256, 0, stream>>>(dstp, et, cnt_i, EE);
    scanA<<<NSB, 256, 0, stream>>>(cnt_i, off, bsum);
    scanB<<<1, 512, 0, stream>>>(bsum, boff);
    scanC<<<NSB, 256, 0, stream>>>(off, boff);
    hipMemcpyAsync(cursor, off, (size_t)NR * sizeof(int),
                   hipMemcpyDeviceToDevice, stream);
    place_kernel<<<(EE + 255) / 256, 256, 0, stream>>>(srcp, dstp, et, cursor,
                                                       srcs, EE);

    // ---- pack weights ----
    bprep_kernel<<<(NCHUNK * 8 * 64 + 255) / 256, 256, 0, stream>>>(w1, root1, Bf1);
    bprep_kernel<<<(NCHUNK * 8 * 64 + 255) / 256, 256, 0, stream>>>(w2, root2, Bf2);

    const int seg_blocks = NR / 4;            // 100000 (4 waves/block, 1 seg/wave)
    const int gemm_blocks = (NN + 63) / 64;   // 782

    // layer 1: x (fp32) -> h (bf16)
    seg_mean<false><<<seg_blocks, 256, 0, stream>>>(x, off, srcs, mean);
    gemm_mfma<false, true><<<gemm_blocks, 256, 0, stream>>>(x, (const u16*)mean,
                                                            Bf1, b1, h);

    // layer 2: h (bf16) -> out (fp32)
    seg_mean<true><<<seg_blocks, 256, 0, stream>>>(h, off, srcs, mean);
    gemm_mfma<true, false><<<gemm_blocks, 256, 0, stream>>>(h, (const u16*)mean,
                                                            Bf2, b2, out);
}

// Round 5
// 423.308 us; speedup vs baseline: 3.0191x; 1.1205x over previous
//
#include <hip/hip_runtime.h>

#define NN 50000
#define D 128
#define EE 600000
#define R 8
#define NR (NN * R)            /* segments, key = dst*R + rel (node-major) */
#define NCHUNK 36              /* 1152 / 32 k-chunks */
#define SCAN_CHUNK 1024
#define NSB ((NR + SCAN_CHUNK - 1) / SCAN_CHUNK) /* 391 */
#define BATCH 8

typedef unsigned short u16;
typedef unsigned int u32;
typedef __attribute__((ext_vector_type(8))) short bf16x8;
typedef __attribute__((ext_vector_type(4))) float f32x4;

__device__ inline u16 f2bf(float f) {
    union { float f; u32 u; } v; v.f = f;
    return (u16)((v.u + 0x7FFFu + ((v.u >> 16) & 1u)) >> 16);
}
__device__ inline float bf2f(u16 h) {
    union { u32 u; float f; } v; v.u = ((u32)h) << 16;
    return v.f;
}

// ---- cast x fp32 -> packed bf16 pairs ----
__global__ __launch_bounds__(256) void xcast_kernel(const float2* __restrict__ x2,
                                                    u32* __restrict__ xb, int n) {
    int i = blockIdx.x * 256 + threadIdx.x;
    if (i < n) {
        float2 v = x2[i];
        xb[i] = (u32)f2bf(v.x) | ((u32)f2bf(v.y) << 16);
    }
}

// ---- histogram per segment key = dst*R + rel ----
__global__ __launch_bounds__(256) void hist_kernel(const int* __restrict__ dst,
                                                   const int* __restrict__ et,
                                                   int* __restrict__ cnt, int E) {
    int e = blockIdx.x * 256 + threadIdx.x;
    if (e < E) atomicAdd(&cnt[dst[e] * R + et[e]], 1);
}

// ---- exclusive scan, 3-pass ----
__global__ __launch_bounds__(256) void scanA(const int* __restrict__ cnt,
                                             int* __restrict__ off,
                                             int* __restrict__ bsum) {
    __shared__ int ts[256];
    const int b = blockIdx.x, t = threadIdx.x;
    const int base = b * SCAN_CHUNK + t * 4;
    int v0 = 0, v1 = 0, v2 = 0, v3 = 0;
    if (base + 3 < NR) {
        int4 q = *(const int4*)(cnt + base);
        v0 = q.x; v1 = q.y; v2 = q.z; v3 = q.w;
    } else {
        if (base < NR) v0 = cnt[base];
        if (base + 1 < NR) v1 = cnt[base + 1];
        if (base + 2 < NR) v2 = cnt[base + 2];
    }
    const int s = v0 + v1 + v2 + v3;
    ts[t] = s;
    __syncthreads();
    for (int d = 1; d < 256; d <<= 1) {
        int x = (t >= d) ? ts[t - d] : 0;
        __syncthreads();
        ts[t] += x;
        __syncthreads();
    }
    const int excl = ts[t] - s;
    if (base < NR) off[base] = excl;
    if (base + 1 < NR) off[base + 1] = excl + v0;
    if (base + 2 < NR) off[base + 2] = excl + v0 + v1;
    if (base + 3 < NR) off[base + 3] = excl + v0 + v1 + v2;
    if (t == 255) bsum[b] = ts[255];
}

__global__ __launch_bounds__(512) void scanB(const int* __restrict__ bsum,
                                             int* __restrict__ boff) {
    __shared__ int ts[512];
    const int t = threadIdx.x;
    const int v = (t < NSB) ? bsum[t] : 0;
    ts[t] = v;
    __syncthreads();
    for (int d = 1; d < 512; d <<= 1) {
        int x = (t >= d) ? ts[t - d] : 0;
        __syncthreads();
        ts[t] += x;
        __syncthreads();
    }
    if (t < NSB) boff[t] = ts[t] - v;
}

// adds block offsets; writes BOTH off and cursor (saves a d2d copy)
__global__ __launch_bounds__(256) void scanC(int* __restrict__ off,
                                             int* __restrict__ cursor,
                                             const int* __restrict__ boff) {
    const int b = blockIdx.x, t = threadIdx.x;
    const int add = boff[b];
    const int base = b * SCAN_CHUNK + t * 4;
#pragma unroll
    for (int j = 0; j < 4; ++j)
        if (base + j < NR) {
            int v = off[base + j] + add;
            off[base + j] = v;
            cursor[base + j] = v;
        }
    if (b == 0 && t == 0) off[NR] = EE;
}

// ---- place edge sources into segment-sorted order ----
__global__ __launch_bounds__(256) void place_kernel(const int* __restrict__ src,
                                                    const int* __restrict__ dst,
                                                    const int* __restrict__ et,
                                                    int* __restrict__ cursor,
                                                    int* __restrict__ ss, int E) {
    int e = blockIdx.x * 256 + threadIdx.x;
    if (e < E) {
        int key = dst[e] * R + et[e];
        int p = atomicAdd(&cursor[key], 1);
        ss[p] = src[e];
    }
}

// ---- pack both layers' B = [w;root] into bf16 MFMA B-fragment order ----
__global__ __launch_bounds__(256) void bprep2_kernel(const float* __restrict__ w1,
                                                     const float* __restrict__ root1,
                                                     u16* __restrict__ Bf1,
                                                     const float* __restrict__ w2,
                                                     const float* __restrict__ root2,
                                                     u16* __restrict__ Bf2) {
    int gidx = blockIdx.x * 256 + threadIdx.x;  // over 2*36*8*64 = 36864
    if (gidx >= 2 * NCHUNK * 8 * 64) return;
    const int layer = gidx / (NCHUNK * 8 * 64);
    const int idx = gidx - layer * (NCHUNK * 8 * 64);
    const float* w = layer ? w2 : w1;
    const float* root = layer ? root2 : root1;
    u16* Bfrag = layer ? Bf2 : Bf1;
    int lane = idx & 63;
    int g = (idx >> 6) & 7;
    int kc = idx >> 9;
    int col = g * 16 + (lane & 15);
    int kbase = kc * 32 + (lane >> 4) * 8;
    u16* o = Bfrag + (size_t)idx * 8;
#pragma unroll
    for (int j = 0; j < 8; ++j) {
        int k = kbase + j;
        float v = (k < R * D) ? w[(size_t)k * D + col]
                              : root[(size_t)(k - R * D) * D + col];
        o[j] = f2bf(v);
    }
}

// ---- segment mean: one WAVE per NODE (8 contiguous segments, ~12 edges) ----
// Batched gather: up to BATCH row-loads in flight per wave; relation id per
// edge is wave-uniform (from CSR boundaries) -> cheap predicated accumulate.
__global__ __launch_bounds__(256) void seg_mean_node(const u32* __restrict__ xb,
                                                     const int* __restrict__ off,
                                                     const int* __restrict__ srcs,
                                                     u32* __restrict__ mean) {
    const int n = blockIdx.x * 4 + (threadIdx.x >> 6);
    const int lane = threadIdx.x & 63;

    int b[9];
#pragma unroll
    for (int r = 0; r <= 8; ++r) b[r] = off[n * 8 + r];
    const int e0 = b[0], e1 = b[8];

    float accx[8], accy[8];
#pragma unroll
    for (int r = 0; r < 8; ++r) { accx[r] = 0.f; accy[r] = 0.f; }

    for (int base = e0; base < e1; base += BATCH) {
        const int m = e1 - base;
        int s[BATCH];
#pragma unroll
        for (int j = 0; j < BATCH; ++j)
            if (j < m) s[j] = srcs[base + j];
        u32 v[BATCH];
#pragma unroll
        for (int j = 0; j < BATCH; ++j)
            if (j < m) v[j] = xb[(size_t)s[j] * (D / 2) + lane];
#pragma unroll
        for (int j = 0; j < BATCH; ++j)
            if (j < m) {
                const int i = base + j;
                int rel = 0;
#pragma unroll
                for (int r = 1; r < 8; ++r) rel += (i >= b[r]);
                const float vx = bf2f((u16)(v[j] & 0xFFFFu));
                const float vy = bf2f((u16)(v[j] >> 16));
#pragma unroll
                for (int r = 0; r < 8; ++r)
                    if (rel == r) { accx[r] += vx; accy[r] += vy; }
            }
    }

#pragma unroll
    for (int r = 0; r < 8; ++r) {
        const int c = b[r + 1] - b[r];
        const float inv = (c > 0) ? 1.0f / (float)c : 0.f;
        mean[((size_t)n * 8 + r) * (D / 2) + lane] =
            (u32)f2bf(accx[r] * inv) | ((u32)f2bf(accy[r] * inv) << 16);
    }
}

// ---- MFMA GEMM: out[n,:] = relu( [mean(n,:,:), xb(n,:)] @ [w;root] + b ) ----
template <bool OUTBF>
__global__ __launch_bounds__(256) void gemm_mfma(const u16* __restrict__ xb,
                                                 const u16* __restrict__ mean,
                                                 const u16* __restrict__ Bfrag,
                                                 const float* __restrict__ bias,
                                                 void* __restrict__ outp) {
    const int t = threadIdx.x;
    const int wave = t >> 6;
    const int lane = t & 63;
    const int quad = lane >> 4;
    const int l15 = lane & 15;
    const int n0 = blockIdx.x * 64;
    const int n = n0 + wave * 16 + l15;
    const int nc = (n < NN) ? n : (NN - 1);  // clamp loads; stores guarded

    f32x4 acc[8];
#pragma unroll
    for (int g = 0; g < 8; ++g) acc[g] = (f32x4){0.f, 0.f, 0.f, 0.f};

    const u16* bbase = Bfrag + (size_t)lane * 8;
    const u16* arow = mean + (size_t)nc * (R * D) + quad * 8;

    // relation part: k = 0..1023, bf16 direct from mean (pre-scaled)
#pragma unroll
    for (int kc = 0; kc < 32; ++kc) {
        bf16x8 af = *(const bf16x8*)(arow + kc * 32);
#pragma unroll
        for (int g = 0; g < 8; ++g) {
            bf16x8 bf = *(const bf16x8*)(bbase + (size_t)(kc * 8 + g) * 512);
            acc[g] = __builtin_amdgcn_mfma_f32_16x16x32_bf16(af, bf, acc[g], 0, 0, 0);
        }
    }

    // root part: k = 1024..1151, bf16 from xb
    {
        const u16* xr = xb + (size_t)nc * D + quad * 8;
#pragma unroll
        for (int c = 0; c < 4; ++c) {
            bf16x8 af = *(const bf16x8*)(xr + c * 32);
            const int kc = 32 + c;
#pragma unroll
            for (int g = 0; g < 8; ++g) {
                bf16x8 bf = *(const bf16x8*)(bbase + (size_t)(kc * 8 + g) * 512);
                acc[g] = __builtin_amdgcn_mfma_f32_16x16x32_bf16(af, bf, acc[g], 0, 0, 0);
            }
        }
    }

    // epilogue: bias + relu; D mapping: row = quad*4 + q, col = g*16 + l15
#pragma unroll
    for (int g = 0; g < 8; ++g) {
        const int col = g * 16 + l15;
        const float bb = bias[col];
#pragma unroll
        for (int q = 0; q < 4; ++q) {
            const int row = n0 + wave * 16 + quad * 4 + q;
            if (row < NN) {
                float v = fmaxf(acc[g][q] + bb, 0.f);
                if (OUTBF)
                    ((u16*)outp)[(size_t)row * D + col] = f2bf(v);
                else
                    ((float*)outp)[(size_t)row * D + col] = v;
            }
        }
    }
}

extern "C" void kernel_launch(void* const* d_in, const int* in_sizes, int n_in,
                              void* d_out, int out_size, void* d_ws, size_t ws_size,
                              hipStream_t stream) {
    const float* x = (const float*)d_in[0];
    const int* ei = (const int*)d_in[1];
    const int* et = (const int*)d_in[2];
    const float* w1 = (const float*)d_in[3];
    const float* root1 = (const float*)d_in[4];
    const float* b1 = (const float*)d_in[5];
    const float* w2 = (const float*)d_in[6];
    const float* root2 = (const float*)d_in[7];
    const float* b2 = (const float*)d_in[8];
    float* out = (float*)d_out;

    char* ws = (char*)d_ws;
    int* off    = (int*)(ws + 0);                  // (NR+1) ints
    int* cnt_i  = (int*)(ws + 1600512);            // NR ints
    int* cursor = (int*)(ws + 3200512);            // NR ints
    int* bsum   = (int*)(ws + 4800512);            // NSB ints
    int* boff   = (int*)(ws + 4802304);            // NSB ints
    int* srcs   = (int*)(ws + 4804096);            // EE ints (2.4 MB)
    u32* xb     = (u32*)(ws + 7204096);            // N*D bf16 = 12.8 MB
    u32* mean   = (u32*)(ws + 20004096);           // N*R*D bf16 = 102.4 MB
    u32* h      = (u32*)(ws + 122404096);          // N*D bf16 = 12.8 MB
    u16* Bf1    = (u16*)(ws + 135204096);          // 294912 B
    u16* Bf2    = (u16*)(ws + 135499008);          // 294912 B

    const int* srcp = ei;
    const int* dstp = ei + EE;

    // ---- input cast + CSR build (shared by both layers) ----
    xcast_kernel<<<(NN * D / 2 + 255) / 256, 256, 0, stream>>>((const float2*)x,
                                                               xb, NN * D / 2);
    hipMemsetAsync(cnt_i, 0, (size_t)NR * sizeof(int), stream);
    hist_kernel<<<(EE + 255) / 256, 256, 0, stream>>>(dstp, et, cnt_i, EE);
    scanA<<<NSB, 256, 0, stream>>>(cnt_i, off, bsum);
    scanB<<<1, 512, 0, stream>>>(bsum, boff);
    scanC<<<NSB, 256, 0, stream>>>(off, cursor, boff);
    place_kernel<<<(EE + 255) / 256, 256, 0, stream>>>(srcp, dstp, et, cursor,
                                                       srcs, EE);
    bprep2_kernel<<<(2 * NCHUNK * 8 * 64 + 255) / 256, 256, 0, stream>>>(
        w1, root1, Bf1, w2, root2, Bf2);

    const int seg_blocks = NN / 4;            // 12500: one wave per node
    const int gemm_blocks = (NN + 63) / 64;   // 782

    // layer 1: xb -> h (bf16)
    seg_mean_node<<<seg_blocks, 256, 0, stream>>>(xb, off, srcs, mean);
    gemm_mfma<true><<<gemm_blocks, 256, 0, stream>>>((const u16*)xb,
                                                     (const u16*)mean, Bf1, b1, h);

    // layer 2: h -> out (fp32)
    seg_mean_node<<<seg_blocks, 256, 0, stream>>>(h, off, srcs, mean);
    gemm_mfma<false><<<gemm_blocks, 256, 0, stream>>>((const u16*)h,
                                                      (const u16*)mean, Bf2, b2, out);
}